// Round 16
// baseline (623.837 us; speedup 1.0000x reference)
//
#include <hip/hip_runtime.h>
#include <math.h>

#define DIM_ 2048
#define HID_ 8192
#define SEQ_ 2048
#define BATCH_ 2
#define TOK_ (BATCH_*SEQ_)

typedef __attribute__((ext_vector_type(4))) float f32x4;
typedef __attribute__((ext_vector_type(16))) float f32x16;
typedef __attribute__((ext_vector_type(8))) __bf16 bf16x8;
typedef __attribute__((ext_vector_type(4))) unsigned int u32x4;
typedef __attribute__((ext_vector_type(4))) short s16x4;
typedef __attribute__((ext_vector_type(8))) short s16x8;
typedef __attribute__((address_space(3))) short* lds_sp;

__device__ __forceinline__ short f2bf(float f) {
  union { float f; unsigned u; } v; v.f = f;
  unsigned r = v.u + 0x7FFFu + ((v.u >> 16) & 1u);
  return (short)(r >> 16);
}
__device__ __forceinline__ float bf2f(short s) {
  union { unsigned u; float f; } v; v.u = ((unsigned)(unsigned short)s) << 16;
  return v.f;
}

__device__ __forceinline__ f32x4 mfma16(u32x4 a, u32x4 b, f32x4 c) {
  return __builtin_amdgcn_mfma_f32_16x16x32_bf16(
      __builtin_bit_cast(bf16x8, a), __builtin_bit_cast(bf16x8, b), c, 0, 0, 0);
}
__device__ __forceinline__ f32x16 mfma32(u32x4 a, u32x4 b, f32x16 c) {
  return __builtin_amdgcn_mfma_f32_32x32x16_bf16(
      __builtin_bit_cast(bf16x8, a), __builtin_bit_cast(bf16x8, b), c, 0, 0, 0);
}

#define DSR(dst, addr) asm volatile("ds_read_b128 %0, %1" : "=v"(dst) : "v"(addr))
#define BARv()  __builtin_amdgcn_s_barrier()
#define LGKMW(n) do { asm volatile("s_waitcnt lgkmcnt(" #n ")" ::: "memory"); \
                      __builtin_amdgcn_sched_barrier(0); } while(0)
#define VM3()   asm volatile("s_waitcnt vmcnt(3)" ::: "memory")
#define VM4()   asm volatile("s_waitcnt vmcnt(4)" ::: "memory")
#define PRIO1() __builtin_amdgcn_s_setprio(1)
#define PRIO0() __builtin_amdgcn_s_setprio(0)
#define AS1 const __attribute__((address_space(1))) void*
#define AS3 __attribute__((address_space(3))) void*

// XCD-chunk + 4-column-group tile mapping (bijective; needs nwg%8==0, gx%4==0)
#define TILE_MAP(BM, BN) \
  const int nwg  = gridDim.x * gridDim.y; \
  const int orig = blockIdx.y * gridDim.x + blockIdx.x; \
  const int wgid = (orig & 7) * (nwg >> 3) + (orig >> 3); \
  const int gy4  = (int)gridDim.y << 2; \
  const int rem  = wgid % gy4; \
  const int tn   = ((wgid / gy4) * 4 + (rem & 3)) * (BN); \
  const int tm   = (rem >> 2) * (BM);

// EPI: 0 bias->bf16 | 1 raw f32 | 2 bias+GELU->bf16 | 3 bias+aux->f32
//      4 scale+mask->bf16 (aux = mask) | 5 raw->bf16
template<int EPI>
__device__ __forceinline__ void epi_store(void* Cv, const float* bias, const float* aux,
                                          int z, long long sC, int ldc, int N,
                                          int row, int col, float v)
{
  if (EPI == 1) {
    ((float*)Cv + (long long)z * sC)[(long long)row * ldc + col] = v;
  } else if (EPI == 0) {
    v += bias[col];
    ((short*)Cv + (long long)z * sC)[(long long)row * ldc + col] = f2bf(v);
  } else if (EPI == 2) {
    v += bias[col];
    v = 0.5f * v * (1.0f + erff(v * 0.70710678118654752f));
    ((short*)Cv + (long long)z * sC)[(long long)row * ldc + col] = f2bf(v);
  } else if (EPI == 3) {
    v += bias[col] + aux[(long long)row * ldc + col];
    ((float*)Cv + (long long)z * sC)[(long long)row * ldc + col] = v;
  } else if (EPI == 4) {
    v = v * 0.022097086912079608f + aux[(long long)row * ldc + col];
    ((short*)Cv + (long long)z * sC)[(long long)row * ldc + col] = f2bf(v);
  } else { // 5
    ((short*)Cv + (long long)z * sC)[(long long)row * ldc + col] = f2bf(v);
  }
}

// ---------------------------------------------------------------------------
// gemm256 (round-8/13 verified, ~820 TF): 256x256 block, BK=32, 8 waves
// (2Mx4N), per-wave 128x64. 3-slot rotation, ONE barrier per K-tile, counted
// lgkmcnt(2)/(0) + vmcnt(4). 0-conflict swizzle both sides. UNCHANGED.
// ---------------------------------------------------------------------------
#define G256_RD1(slot) do { \
  const unsigned s_ = (unsigned)(slot)*16384u; \
  DSR(af[0], aRd + s_);          DSR(af[1], aRd + s_ + 1024u); \
  DSR(af[2], aRd + s_ + 2048u);  DSR(af[3], aRd + s_ + 3072u); \
  DSR(af[4], aRd + s_ + 4096u);  DSR(af[5], aRd + s_ + 5120u); \
  DSR(af[6], aRd + s_ + 6144u);  DSR(af[7], aRd + s_ + 7168u); \
  DSR(bf0[0], bRd + s_);         DSR(bf0[1], bRd + s_ + 1024u); \
} while(0)

#define G256_RD2(slot) do { \
  const unsigned s_ = (unsigned)(slot)*16384u; \
  DSR(bf1[0], bRd + s_ + 2048u); DSR(bf1[1], bRd + s_ + 3072u); \
} while(0)

#define G256_MM(c0, bA, bB) do { \
  _Pragma("unroll") \
  for (int fr_ = 0; fr_ < 8; ++fr_) { \
    acc[fr_][(c0)]   = mfma16(af[fr_], bA, acc[fr_][(c0)]); \
    acc[fr_][(c0)+1] = mfma16(af[fr_], bB, acc[fr_][(c0)+1]); \
  } \
} while(0)

template<int EPI>
__global__ __launch_bounds__(512, 2)
void gemm256(const short* __restrict__ A, const short* __restrict__ B,
             void* __restrict__ Cv, const float* __restrict__ bias,
             const float* __restrict__ aux,
             int M, int N, int K, int lda, int ldb, int ldc,
             long long sA, long long sB, long long sC)
{
  __shared__ __align__(16) short As[3*256*32];   // 48 KB
  __shared__ __align__(16) short Bs[3*256*32];   // 48 KB
  const int lane = threadIdx.x & 63;
  const int wave = threadIdx.x >> 6;
  const int wr = wave >> 2, wc = wave & 3;       // 2M x 4N, per-wave 128x64
  TILE_MAP(256, 256)
  const int z = blockIdx.z;
  A += (long long)z * sA;
  B += (long long)z * sB;

  const int NT = K >> 5;

  const int rr   = wave * 16 + (lane >> 2);
  const int soff = (((lane & 3) ^ ((lane >> 3) & 3)) << 3);   // elements
  const short* pA = A + (long long)(tm + rr) * lda + soff;
  const short* pB = B + (long long)(tn + rr) * ldb + soff;
  const long long lda128 = 128LL * lda;
  const long long ldb128 = 128LL * ldb;

  auto stA = [&](int t, int slot) {
    const long long ko = (long long)t << 5;
    __builtin_amdgcn_global_load_lds((AS1)(pA + ko),
        (AS3)(As + slot * 8192 + wave * 512), 16, 0, 0);
    __builtin_amdgcn_global_load_lds((AS1)(pA + lda128 + ko),
        (AS3)(As + slot * 8192 + 4096 + wave * 512), 16, 0, 0);
  };
  auto stB = [&](int t, int slot) {
    const long long ko = (long long)t << 5;
    __builtin_amdgcn_global_load_lds((AS1)(pB + ko),
        (AS3)(Bs + slot * 8192 + wave * 512), 16, 0, 0);
    __builtin_amdgcn_global_load_lds((AS1)(pB + ldb128 + ko),
        (AS3)(Bs + slot * 8192 + 4096 + wave * 512), 16, 0, 0);
  };

  const unsigned asB = (unsigned)(unsigned long long)(lds_sp)As;
  const unsigned bsB = (unsigned)(unsigned long long)(lds_sp)Bs;
  const int l15 = lane & 15, l4 = lane >> 4;
  const unsigned offk = (unsigned)((l4 ^ ((l15 >> 1) & 3)) << 4);
  const unsigned aRd = asB + (unsigned)((wr * 128 + l15) * 64) + offk;
  const unsigned bRd = bsB + (unsigned)((wc * 64 + l15) * 64) + offk;

  f32x4 acc[8][4] = {};
  u32x4 af[8], bf0[2], bf1[2];

  stA(0, 0); stB(0, 0);
  stA(1 < NT ? 1 : 0, 1); stB(1 < NT ? 1 : 0, 1);
  VM4();
  BARv();

  int rd = 0;
  #pragma unroll 1
  for (int t = 0; t < NT; ++t) {
    const int st = rd + 2 >= 3 ? rd - 1 : rd + 2;   // (t+2)%3
    const int tc = t + 2 < NT ? t + 2 : NT - 1;
    G256_RD1(rd);
    G256_RD2(rd);
    stA(tc, st); stB(tc, st);
    LGKMW(2);
    PRIO1(); G256_MM(0, bf0[0], bf0[1]);
    LGKMW(0);
    G256_MM(2, bf1[0], bf1[1]); PRIO0();
    VM4();
    BARv();
    rd = rd + 1 >= 3 ? 0 : rd + 1;
  }

  const int row0 = tm + wr * 128 + l4 * 4;
  const int col0 = tn + wc * 64 + l15;
  #pragma unroll
  for (int fr = 0; fr < 8; ++fr)
    #pragma unroll
    for (int j = 0; j < 4; ++j)
      #pragma unroll
      for (int fc = 0; fc < 4; ++fc)
        epi_store<EPI>(Cv, bias, aux, z, sC, ldc, N,
                       row0 + fr * 16 + j, col0 + fc * 16, acc[fr][fc][j]);
}

// ---------------------------------------------------------------------------
// gemm_bn128 (round-12/13 verified): 256x128 block, per-wave 128x32, 3-slot
// rotation. QKV grid 48x16 = 768 wg = 3 full dispatch rounds. UNCHANGED.
// ---------------------------------------------------------------------------
template<int EPI>
__global__ __launch_bounds__(512, 2)
void gemm_bn128(const short* __restrict__ A, const short* __restrict__ B,
                void* __restrict__ Cv, const float* __restrict__ bias,
                const float* __restrict__ aux,
                int M, int N, int K, int lda, int ldb, int ldc,
                long long sA, long long sB, long long sC)
{
  __shared__ __align__(16) short As[3*256*32];   // 48 KB
  __shared__ __align__(16) short Bs[3*256*32];   // 48 KB (half used)
  const int lane = threadIdx.x & 63;
  const int wave = threadIdx.x >> 6;
  const int wr = wave >> 2, wc = wave & 3;       // per-wave 128 x 32
  TILE_MAP(256, 128)
  const int z = blockIdx.z;
  A += (long long)z * sA;
  B += (long long)z * sB;

  const int NT = K >> 5;

  const int rr   = wave * 16 + (lane >> 2);
  const int soff = (((lane & 3) ^ ((lane >> 3) & 3)) << 3);
  const short* pA = A + (long long)(tm + rr) * lda + soff;
  const short* pB = B + (long long)(tn + rr) * ldb + soff;
  const long long lda128 = 128LL * lda;

  auto stage = [&](int t, int slot) {
    const long long ko = (long long)t << 5;
    __builtin_amdgcn_global_load_lds((AS1)(pA + ko),
        (AS3)(As + slot * 8192 + wave * 512), 16, 0, 0);
    __builtin_amdgcn_global_load_lds((AS1)(pA + lda128 + ko),
        (AS3)(As + slot * 8192 + 4096 + wave * 512), 16, 0, 0);
    __builtin_amdgcn_global_load_lds((AS1)(pB + ko),
        (AS3)(Bs + slot * 8192 + wave * 512), 16, 0, 0);
  };

  const unsigned asB = (unsigned)(unsigned long long)(lds_sp)As;
  const unsigned bsB = (unsigned)(unsigned long long)(lds_sp)Bs;
  const int l15 = lane & 15, l4 = lane >> 4;
  const unsigned offk = (unsigned)((l4 ^ ((l15 >> 1) & 3)) << 4);
  const unsigned aRd = asB + (unsigned)((wr * 128 + l15) * 64) + offk;
  const unsigned bRd = bsB + (unsigned)((wc * 32 + l15) * 64) + offk;

  f32x4 acc[8][2] = {};
  u32x4 af[8], bf[2];

  stage(0, 0);
  stage(1 < NT ? 1 : 0, 1);
  VM3();
  BARv();

  int rd = 0;
  #pragma unroll 1
  for (int t = 0; t < NT; ++t) {
    const int st = rd + 2 >= 3 ? rd - 1 : rd + 2;
    const int tc = t + 2 < NT ? t + 2 : NT - 1;
    {
      const unsigned s_ = (unsigned)rd * 16384u;
      DSR(bf[0], bRd + s_);          DSR(bf[1], bRd + s_ + 1024u);
      DSR(af[0], aRd + s_);          DSR(af[1], aRd + s_ + 1024u);
      DSR(af[2], aRd + s_ + 2048u);  DSR(af[3], aRd + s_ + 3072u);
      DSR(af[4], aRd + s_ + 4096u);  DSR(af[5], aRd + s_ + 5120u);
      DSR(af[6], aRd + s_ + 6144u);  DSR(af[7], aRd + s_ + 7168u);
    }
    stage(tc, st);
    LGKMW(4);
    PRIO1();
    #pragma unroll
    for (int fr = 0; fr < 4; ++fr) {
      acc[fr][0] = mfma16(af[fr], bf[0], acc[fr][0]);
      acc[fr][1] = mfma16(af[fr], bf[1], acc[fr][1]);
    }
    LGKMW(0);
    #pragma unroll
    for (int fr = 4; fr < 8; ++fr) {
      acc[fr][0] = mfma16(af[fr], bf[0], acc[fr][0]);
      acc[fr][1] = mfma16(af[fr], bf[1], acc[fr][1]);
    }
    PRIO0();
    VM3();
    BARv();
    rd = rd + 1 >= 3 ? 0 : rd + 1;
  }

  const int row0 = tm + wr * 128 + l4 * 4;
  const int col0 = tn + wc * 32 + l15;
  #pragma unroll
  for (int fr = 0; fr < 8; ++fr)
    #pragma unroll
    for (int j = 0; j < 4; ++j)
      #pragma unroll
      for (int fc = 0; fc < 2; ++fc)
        epi_store<EPI>(Cv, bias, aux, z, sC, ldc, N,
                       row0 + fr * 16 + j, col0 + fc * 16, acc[fr][fc][j]);
}

// ---------------------------------------------------------------------------
// gemm_hi (ROUND-16: 32x32x16 MFMA core): 128x256 tile, BK=32, 3-slot
// rotation, 72KB LDS -> 2 wg/CU. Per-wave 64x64 = 2x2 fragments of 32x32;
// 8 MFMA/tile (was 16), same LDS traffic/addresses family.
// Fragment reads: row = frag*32 + (l&31); k-half l5=(l>>5); logical 16B-slot
// = ks*2+l5; phys = logical ^ ((l&31)>>1)&3 (same swizzle; wc*64/ni*32 are
// multiples of 32 so g depends only on l&31). C/D: col=lane&31,
// row=(reg&3)+8*(reg>>2)+4*(lane>>5) (m74/m101 verified).
// CZ: 0 dense | 1 causal tile-skip | 2 causal K-cap.
// ---------------------------------------------------------------------------
template<int EPI, int CZ>
__global__ __launch_bounds__(512, 4)
void gemm_hi(const short* __restrict__ A, const short* __restrict__ B,
             void* __restrict__ Cv, const float* __restrict__ bias,
             const float* __restrict__ aux,
             int M, int N, int K, int lda, int ldb, int ldc,
             long long sA, long long sB, long long sC)
{
  __shared__ __align__(16) short As[3*128*32];   // 24 KB
  __shared__ __align__(16) short Bs[3*256*32];   // 48 KB
  const int lane = threadIdx.x & 63;
  const int wave = threadIdx.x >> 6;
  const int wr = wave >> 2, wc = wave & 3;
  TILE_MAP(128, 256)
  if (CZ == 1 && tn >= tm + 128) return;
  const int z = blockIdx.z;
  A += (long long)z * sA;
  B += (long long)z * sB;

  const int NT = (CZ == 2) ? ((tm + 128) >> 5) : (K >> 5);

  const int rr   = wave * 16 + (lane >> 2);
  const int soff = (((lane & 3) ^ ((lane >> 3) & 3)) << 3);
  const short* pA = A + (long long)(tm + rr) * lda + soff;
  const short* pB = B + (long long)(tn + rr) * ldb + soff;
  const long long ldb128 = 128LL * ldb;

  auto stage = [&](int t, int slot) {
    const long long ko = (long long)t << 5;
    __builtin_amdgcn_global_load_lds((AS1)(pA + ko),
        (AS3)(As + slot * 4096 + wave * 512), 16, 0, 0);
    __builtin_amdgcn_global_load_lds((AS1)(pB + ko),
        (AS3)(Bs + slot * 8192 + wave * 512), 16, 0, 0);
    __builtin_amdgcn_global_load_lds((AS1)(pB + ldb128 + ko),
        (AS3)(Bs + slot * 8192 + 4096 + wave * 512), 16, 0, 0);
  };

  // 32x32 fragment addressing
  const unsigned asB = (unsigned)(unsigned long long)(lds_sp)As;
  const unsigned bsB = (unsigned)(unsigned long long)(lds_sp)Bs;
  const int l31 = lane & 31, l5 = lane >> 5;
  const unsigned g  = (unsigned)((l31 >> 1) & 3);
  const unsigned o0 = (((unsigned)(0 * 2 + l5) ^ g) << 4);   // ks=0 byte off
  const unsigned o1 = (((unsigned)(1 * 2 + l5) ^ g) << 4);   // ks=1 byte off
  const unsigned aB32 = asB + (unsigned)((wr * 64 + l31) * 64);
  const unsigned bB32 = bsB + (unsigned)((wc * 64 + l31) * 64);

  f32x16 acc[2][2] = {};
  u32x4 af[2][2], bf[2][2];   // [frag][ks]

  stage(0, 0);
  stage(1 < NT ? 1 : 0, 1);
  VM3();
  BARv();

  int rd = 0;
  #pragma unroll 1
  for (int t = 0; t < NT; ++t) {
    const int st = rd + 2 >= 3 ? rd - 1 : rd + 2;
    const int tc = t + 2 < NT ? t + 2 : NT - 1;
    {
      const unsigned a_ = aB32 + (unsigned)rd * 8192u;
      const unsigned b_ = bB32 + (unsigned)rd * 16384u;
      DSR(bf[0][0], b_ + o0);          DSR(bf[0][1], b_ + o1);
      DSR(bf[1][0], b_ + 2048u + o0);  DSR(bf[1][1], b_ + 2048u + o1);
      DSR(af[0][0], a_ + o0);          DSR(af[0][1], a_ + o1);
      DSR(af[1][0], a_ + 2048u + o0);  DSR(af[1][1], a_ + 2048u + o1);
    }
    stage(tc, st);
    LGKMW(3);                 // bf all + af[0][0]
    PRIO1();
    acc[0][0] = mfma32(af[0][0], bf[0][0], acc[0][0]);
    acc[0][1] = mfma32(af[0][0], bf[1][0], acc[0][1]);
    LGKMW(2);                 // af[0][1]
    acc[0][0] = mfma32(af[0][1], bf[0][1], acc[0][0]);
    acc[0][1] = mfma32(af[0][1], bf[1][1], acc[0][1]);
    LGKMW(1);                 // af[1][0]
    acc[1][0] = mfma32(af[1][0], bf[0][0], acc[1][0]);
    acc[1][1] = mfma32(af[1][0], bf[1][0], acc[1][1]);
    LGKMW(0);                 // af[1][1]
    acc[1][0] = mfma32(af[1][1], bf[0][1], acc[1][0]);
    acc[1][1] = mfma32(af[1][1], bf[1][1], acc[1][1]);
    PRIO0();
    VM3();
    BARv();
    rd = rd + 1 >= 3 ? 0 : rd + 1;
  }

  // epilogue: col = lane&31, row = (reg&3) + 8*(reg>>2) + 4*(lane>>5)
  #pragma unroll
  for (int mi = 0; mi < 2; ++mi) {
    const int rbase = tm + wr * 64 + mi * 32 + 4 * l5;
    #pragma unroll
    for (int ni = 0; ni < 2; ++ni) {
      const int col = tn + wc * 64 + ni * 32 + l31;
      #pragma unroll
      for (int r = 0; r < 16; ++r) {
        const int row = rbase + (r & 3) + 8 * (r >> 2);
        epi_store<EPI>(Cv, bias, aux, z, sC, ldc, N, row, col, acc[mi][ni][r]);
      }
    }
  }
}

// ---------------------------------------------------------------------------
// LayerNorm: out_bf16[row] = LN(x[row] (+ res)) * g + b
// hasres: 0 none | 1 res f32 | 2 res bf16
// ---------------------------------------------------------------------------
__global__ __launch_bounds__(256)
void ln_kernel(const float* __restrict__ x, const void* __restrict__ res,
               const float* __restrict__ g, const float* __restrict__ b,
               short* __restrict__ out, int hasres)
{
  const int row = blockIdx.x;
  const int tid = threadIdx.x;
  const float4* X = (const float4*)x + (long long)row * 512;
  float4 v0 = X[tid], v1 = X[tid + 256];
  if (hasres == 1) {
    const float4* R = (const float4*)res + (long long)row * 512;
    float4 r0 = R[tid], r1 = R[tid + 256];
    v0.x += r0.x; v0.y += r0.y; v0.z += r0.z; v0.w += r0.w;
    v1.x += r1.x; v1.y += r1.y; v1.z += r1.z; v1.w += r1.w;
  } else if (hasres == 2) {
    const short* R = (const short*)res + (long long)row * 2048;
    s16x4 r0 = *(const s16x4*)&R[tid * 4];
    s16x4 r1 = *(const s16x4*)&R[1024 + tid * 4];
    v0.x += bf2f(r0[0]); v0.y += bf2f(r0[1]); v0.z += bf2f(r0[2]); v0.w += bf2f(r0[3]);
    v1.x += bf2f(r1[0]); v1.y += bf2f(r1[1]); v1.z += bf2f(r1[2]); v1.w += bf2f(r1[3]);
  }
  float s1 = v0.x + v0.y + v0.z + v0.w + v1.x + v1.y + v1.z + v1.w;
  float s2 = v0.x*v0.x + v0.y*v0.y + v0.z*v0.z + v0.w*v0.w
           + v1.x*v1.x + v1.y*v1.y + v1.z*v1.z + v1.w*v1.w;
  #pragma unroll
  for (int o = 32; o > 0; o >>= 1) { s1 += __shfl_xor(s1, o); s2 += __shfl_xor(s2, o); }
  __shared__ float red[8];
  if ((tid & 63) == 0) { red[tid >> 6] = s1; red[4 + (tid >> 6)] = s2; }
  __syncthreads();
  s1 = red[0] + red[1] + red[2] + red[3];
  s2 = red[4] + red[5] + red[6] + red[7];
  const float mean = s1 * (1.0f / 2048.0f);
  const float var  = s2 * (1.0f / 2048.0f) - mean * mean;
  const float rstd = rsqrtf(var + 1e-5f);
  const float4* G  = (const float4*)g;
  const float4* Bb = (const float4*)b;
  float4 g0 = G[tid], g1 = G[tid + 256], b0 = Bb[tid], b1 = Bb[tid + 256];
  s16x4 o0, o1;
  o0[0] = f2bf((v0.x - mean) * rstd * g0.x + b0.x);
  o0[1] = f2bf((v0.y - mean) * rstd * g0.y + b0.y);
  o0[2] = f2bf((v0.z - mean) * rstd * g0.z + b0.z);
  o0[3] = f2bf((v0.w - mean) * rstd * g0.w + b0.w);
  o1[0] = f2bf((v1.x - mean) * rstd * g1.x + b1.x);
  o1[1] = f2bf((v1.y - mean) * rstd * g1.y + b1.y);
  o1[2] = f2bf((v1.z - mean) * rstd * g1.z + b1.z);
  o1[3] = f2bf((v1.w - mean) * rstd * g1.w + b1.w);
  *(s16x4*)&out[(long long)row * 2048 + tid * 4]        = o0;
  *(s16x4*)&out[(long long)row * 2048 + 1024 + tid * 4] = o1;
}

// ---------------------------------------------------------------------------
// Causal in-place softmax over bf16 rows (round-13 verified)
// ---------------------------------------------------------------------------
__global__ __launch_bounds__(256)
void softmax_causal_kernel(short* __restrict__ probs)
{
  const long long row = blockIdx.x;
  const int q  = blockIdx.x & (SEQ_ - 1);
  const int tid = threadIdx.x;
  short* P = probs + row * 2048 + tid * 8;
  const int kbase = tid * 8;
  s16x8 in = *(const s16x8*)P;
  float a[8];
  #pragma unroll
  for (int i = 0; i < 8; ++i) a[i] = bf2f(in[i]);
  float mx = -1e30f;
  #pragma unroll
  for (int i = 0; i < 8; ++i) {
    const float av = (kbase + i <= q) ? a[i] : -1e30f;
    mx = fmaxf(mx, av);
  }
  #pragma unroll
  for (int o = 32; o > 0; o >>= 1) mx = fmaxf(mx, __shfl_xor(mx, o));
  __shared__ float red[8];
  if ((tid & 63) == 0) red[tid >> 6] = mx;
  __syncthreads();
  mx = fmaxf(fmaxf(red[0], red[1]), fmaxf(red[2], red[3]));
  float e[8], sum = 0.f;
  #pragma unroll
  for (int i = 0; i < 8; ++i) {
    e[i] = (kbase + i <= q) ? __expf(a[i] - mx) : 0.f;
    sum += e[i];
  }
  #pragma unroll
  for (int o = 32; o > 0; o >>= 1) sum += __shfl_xor(sum, o);
  if ((tid & 63) == 0) red[4 + (tid >> 6)] = sum;
  __syncthreads();
  sum = red[4] + red[5] + red[6] + red[7];
  const float inv = 1.0f / sum;
  s16x8 o;
  #pragma unroll
  for (int i = 0; i < 8; ++i) o[i] = f2bf(e[i] * inv);
  *(s16x8*)P = o;
}

// ---------------------------------------------------------------------------
// fp32 (R,C) -> bf16 (C,R) transpose-convert, 64x64 tiles, float4 loads.
// Batched 3-input variant for wq/wk/wv.
// ---------------------------------------------------------------------------
__device__ __forceinline__ void cvt_t64_body(const float* in, short* out, int R, int C)
{
  __shared__ float t[64][69];
  const int r0 = blockIdx.y << 6, c0 = blockIdx.x << 6;
  const int tx = threadIdx.x & 15, ty = threadIdx.x >> 4;
  #pragma unroll
  for (int p = 0; p < 4; ++p) {
    const int r = ty + p * 16;
    float4 v = *(const float4*)&in[(long long)(r0 + r) * C + c0 + tx * 4];
    t[r][tx*4+0] = v.x; t[r][tx*4+1] = v.y; t[r][tx*4+2] = v.z; t[r][tx*4+3] = v.w;
  }
  __syncthreads();
  #pragma unroll
  for (int p = 0; p < 4; ++p) {
    const int oc = ty + p * 16;
    s16x4 o;
    o[0] = f2bf(t[tx*4+0][oc]); o[1] = f2bf(t[tx*4+1][oc]);
    o[2] = f2bf(t[tx*4+2][oc]); o[3] = f2bf(t[tx*4+3][oc]);
    *(s16x4*)&out[(long long)(c0 + oc) * R + r0 + tx * 4] = o;
  }
}

__global__ __launch_bounds__(256)
void cvt_transpose64(const float* __restrict__ in, short* __restrict__ out,
                     int R, int C)
{ cvt_t64_body(in, out, R, C); }

__global__ __launch_bounds__(256)
void cvt3_transpose64(const float* __restrict__ a, const float* __restrict__ b,
                      const float* __restrict__ c, short* __restrict__ out)
{
  const int z = blockIdx.z;
  const float* in = z == 0 ? a : (z == 1 ? b : c);
  cvt_t64_body(in, out + (size_t)z * DIM_ * DIM_, DIM_, DIM_);
}

// bf16 strided (z,R,C) -> (z,C,R) transpose (V)
__global__ __launch_bounds__(256)
void transpose_bf16_kernel(const short* __restrict__ in, short* __restrict__ out,
                           int ldin, int ldout, long long sin_, long long sout_)
{
  __shared__ short t[32][33];
  in  += (long long)blockIdx.z * sin_;
  out += (long long)blockIdx.z * sout_;
  const int tx = threadIdx.x & 31, ty = threadIdx.x >> 5;
  const int r0 = blockIdx.y << 5, c0 = blockIdx.x << 5;
  #pragma unroll
  for (int i = 0; i < 32; i += 8)
    t[ty + i][tx] = in[(long long)(r0 + ty + i) * ldin + c0 + tx];
  __syncthreads();
  #pragma unroll
  for (int i = 0; i < 32; i += 8)
    out[(long long)(c0 + ty + i) * ldout + r0 + tx] = t[tx][ty + i];
}

__global__ __launch_bounds__(256)
void concat_bias_kernel(const float* a, const float* b, const float* c, float* o)
{
  const int i = blockIdx.x * 256 + threadIdx.x;   // 6144
  o[i] = i < 2048 ? a[i] : (i < 4096 ? b[i - 2048] : c[i - 4096]);
}

// ---------------------------------------------------------------------------
extern "C" void kernel_launch(void* const* d_in, const int* in_sizes, int n_in,
                              void* d_out, int out_size, void* d_ws, size_t ws_size,
                              hipStream_t stream)
{
  const float* x    = (const float*)d_in[0];
  const float* mask = (const float*)d_in[1];
  const float* wq   = (const float*)d_in[4];
  const float* bq   = (const float*)d_in[5];
  const float* wk   = (const float*)d_in[6];
  const float* bk   = (const float*)d_in[7];
  const float* wv   = (const float*)d_in[8];
  const float* bv   = (const float*)d_in[9];
  const float* g1   = (const float*)d_in[10];
  const float* b1   = (const float*)d_in[11];
  const float* g2   = (const float*)d_in[12];
  const float* b2   = (const float*)d_in[13];
  const float* w1   = (const float*)d_in[14];
  const float* bw1  = (const float*)d_in[15];
  const float* w2   = (const float*)d_in[16];
  const float* bw2  = (const float*)d_in[17];
  float* out = (float*)d_out;

  char* p = (char*)d_ws;
  auto take = [&](size_t bytes) { char* r = p; p += (bytes + 255) & ~(size_t)255; return r; };
  short* wqkvT = (short*)take((size_t)3 * DIM_ * DIM_ * 2);  // [6144][2048] bf16
  short* w1T   = (short*)take((size_t)DIM_ * HID_ * 2);      // [8192][2048]
  short* w2T   = (short*)take((size_t)HID_ * DIM_ * 2);      // [2048][8192]
  short* h_bf  = (short*)take((size_t)TOK_ * DIM_ * 2);      // reused as h2
  short* qkv   = (short*)take((size_t)TOK_ * 3 * DIM_ * 2);  // [4096][6144]
  short* vT    = (short*)take((size_t)BATCH_ * DIM_ * SEQ_ * 2);
  short* attno = (short*)take((size_t)TOK_ * DIM_ * 2);      // bf16
  short* attn  = (short*)take((size_t)BATCH_ * SEQ_ * SEQ_ * 2);
  float* cbias = (float*)take((size_t)3 * DIM_ * 4);
  short* ffn1  = qkv;          // alias over qkv+vT (dead after PV)
  short* h2    = h_bf;         // alias (h dead after QKV)

  const dim3 blk(256), gblk(512);
  // weight convert+transpose (batched QKV + w1 + w2)
  cvt3_transpose64<<<dim3(DIM_/64, DIM_/64, 3), blk, 0, stream>>>(wq, wk, wv, wqkvT);
  cvt_transpose64<<<dim3(HID_/64, DIM_/64), blk, 0, stream>>>(w1, w1T, DIM_, HID_);
  cvt_transpose64<<<dim3(DIM_/64, HID_/64), blk, 0, stream>>>(w2, w2T, HID_, DIM_);
  concat_bias_kernel<<<24, blk, 0, stream>>>(bq, bk, bv, cbias);
  // LN1
  ln_kernel<<<TOK_, blk, 0, stream>>>(x, nullptr, g1, b1, h_bf, 0);
  // fused QKV (gemm_bn128 3-slot, 768 wg = 3 full rounds)
  gemm_bn128<0><<<dim3(6144/128, TOK_/256, 1), gblk, 0, stream>>>(
      h_bf, wqkvT, qkv, cbias, nullptr, TOK_, 6144, DIM_, DIM_, DIM_, 6144, 0, 0, 0);
  // scores (scale+mask fused, causal skip) -> bf16 attn  [32x32 core]
  gemm_hi<4,1><<<dim3(SEQ_/256, SEQ_/128, BATCH_), gblk, 0, stream>>>(
      qkv, qkv + DIM_, attn, nullptr, mask, SEQ_, SEQ_, DIM_, 6144, 6144, SEQ_,
      (long long)SEQ_ * 6144, (long long)SEQ_ * 6144, (long long)SEQ_ * SEQ_);
  // causal in-place softmax
  softmax_causal_kernel<<<BATCH_ * SEQ_, blk, 0, stream>>>(attn);
  // V transpose: (B,S,D) strided in qkv -> vT (B,D,S)
  transpose_bf16_kernel<<<dim3(DIM_/32, SEQ_/32, BATCH_), blk, 0, stream>>>(
      qkv + 2*DIM_, vT, 6144, SEQ_, (long long)SEQ_ * 6144, (long long)DIM_ * SEQ_);
  // attn_out = probs @ V (causal K-cap) -> bf16  [32x32 core]
  gemm_hi<5,2><<<dim3(DIM_/256, SEQ_/128, BATCH_), gblk, 0, stream>>>(
      attn, vT, attno, nullptr, nullptr, SEQ_, DIM_, SEQ_, SEQ_, SEQ_, DIM_,
      (long long)SEQ_ * SEQ_, (long long)DIM_ * SEQ_, (long long)SEQ_ * DIM_);
  // LN2 over x + attn_out(bf16)
  ln_kernel<<<TOK_, blk, 0, stream>>>(x, attno, g2, b2, h2, 2);
  // FFN1 (gemm256 3-slot): gelu(h2 @ w1 + b1) -> bf16
  gemm256<2><<<dim3(HID_/256, TOK_/256, 1), gblk, 0, stream>>>(
      h2, w1T, ffn1, bw1, nullptr, TOK_, HID_, DIM_, DIM_, DIM_, HID_, 0, 0, 0);
  // FFN2 (gemm_hi 3-slot, 2 wg/CU) [32x32 core]: x + (ffn1 @ w2 + b2) -> f32
  gemm_hi<3,0><<<dim3(DIM_/256, TOK_/128, 1), gblk, 0, stream>>>(
      ffn1, w2T, out, bw2, x, TOK_, DIM_, HID_, HID_, HID_, DIM_, 0, 0, 0);
}

// Round 17
// 609.097 us; speedup vs baseline: 1.0242x; 1.0242x over previous
//
#include <hip/hip_runtime.h>
#include <math.h>

#define DIM_ 2048
#define HID_ 8192
#define SEQ_ 2048
#define BATCH_ 2
#define TOK_ (BATCH_*SEQ_)

typedef __attribute__((ext_vector_type(4))) float f32x4;
typedef __attribute__((ext_vector_type(8))) __bf16 bf16x8;
typedef __attribute__((ext_vector_type(4))) unsigned int u32x4;
typedef __attribute__((ext_vector_type(4))) short s16x4;
typedef __attribute__((ext_vector_type(8))) short s16x8;
typedef __attribute__((address_space(3))) short* lds_sp;

__device__ __forceinline__ short f2bf(float f) {
  union { float f; unsigned u; } v; v.f = f;
  unsigned r = v.u + 0x7FFFu + ((v.u >> 16) & 1u);
  return (short)(r >> 16);
}
__device__ __forceinline__ float bf2f(short s) {
  union { unsigned u; float f; } v; v.u = ((unsigned)(unsigned short)s) << 16;
  return v.f;
}

__device__ __forceinline__ f32x4 mfma16(u32x4 a, u32x4 b, f32x4 c) {
  return __builtin_amdgcn_mfma_f32_16x16x32_bf16(
      __builtin_bit_cast(bf16x8, a), __builtin_bit_cast(bf16x8, b), c, 0, 0, 0);
}

#define DSR(dst, addr) asm volatile("ds_read_b128 %0, %1" : "=v"(dst) : "v"(addr))
#define BARv()  __builtin_amdgcn_s_barrier()
#define LGKMW(n) do { asm volatile("s_waitcnt lgkmcnt(" #n ")" ::: "memory"); \
                      __builtin_amdgcn_sched_barrier(0); } while(0)
#define VM3()   asm volatile("s_waitcnt vmcnt(3)" ::: "memory")
#define VM4()   asm volatile("s_waitcnt vmcnt(4)" ::: "memory")
#define PRIO1() __builtin_amdgcn_s_setprio(1)
#define PRIO0() __builtin_amdgcn_s_setprio(0)
#define AS1 const __attribute__((address_space(1))) void*
#define AS3 __attribute__((address_space(3))) void*

// XCD-chunk + 4-column-group tile mapping (bijective; needs nwg%8==0, gx%4==0)
#define TILE_MAP(BM, BN) \
  const int nwg  = gridDim.x * gridDim.y; \
  const int orig = blockIdx.y * gridDim.x + blockIdx.x; \
  const int wgid = (orig & 7) * (nwg >> 3) + (orig >> 3); \
  const int gy4  = (int)gridDim.y << 2; \
  const int rem  = wgid % gy4; \
  const int tn   = ((wgid / gy4) * 4 + (rem & 3)) * (BN); \
  const int tm   = (rem >> 2) * (BM);

// EPI: 0 bias->bf16 | 1 raw f32 | 2 bias+GELU->bf16 | 3 bias+aux->f32
//      4 scale+mask->bf16 (aux = mask) | 5 raw->bf16
template<int EPI>
__device__ __forceinline__ void epi_store(void* Cv, const float* bias, const float* aux,
                                          int z, long long sC, int ldc, int N,
                                          int row, int col, float v)
{
  if (EPI == 1) {
    ((float*)Cv + (long long)z * sC)[(long long)row * ldc + col] = v;
  } else if (EPI == 0) {
    v += bias[col];
    ((short*)Cv + (long long)z * sC)[(long long)row * ldc + col] = f2bf(v);
  } else if (EPI == 2) {
    v += bias[col];
    v = 0.5f * v * (1.0f + erff(v * 0.70710678118654752f));
    ((short*)Cv + (long long)z * sC)[(long long)row * ldc + col] = f2bf(v);
  } else if (EPI == 3) {
    v += bias[col] + aux[(long long)row * ldc + col];
    ((float*)Cv + (long long)z * sC)[(long long)row * ldc + col] = v;
  } else if (EPI == 4) {
    v = v * 0.022097086912079608f + aux[(long long)row * ldc + col];
    ((short*)Cv + (long long)z * sC)[(long long)row * ldc + col] = f2bf(v);
  } else { // 5
    ((short*)Cv + (long long)z * sC)[(long long)row * ldc + col] = f2bf(v);
  }
}

// ---------------------------------------------------------------------------
// gemm256 (round-8/13 verified, ~820 TF): 256x256 block, BK=32, 8 waves
// (2Mx4N), per-wave 128x64. 3-slot rotation, ONE barrier per K-tile, counted
// lgkmcnt(2)/(0) + vmcnt(4). 0-conflict swizzle both sides.
// ---------------------------------------------------------------------------
#define G256_RD1(slot) do { \
  const unsigned s_ = (unsigned)(slot)*16384u; \
  DSR(af[0], aRd + s_);          DSR(af[1], aRd + s_ + 1024u); \
  DSR(af[2], aRd + s_ + 2048u);  DSR(af[3], aRd + s_ + 3072u); \
  DSR(af[4], aRd + s_ + 4096u);  DSR(af[5], aRd + s_ + 5120u); \
  DSR(af[6], aRd + s_ + 6144u);  DSR(af[7], aRd + s_ + 7168u); \
  DSR(bf0[0], bRd + s_);         DSR(bf0[1], bRd + s_ + 1024u); \
} while(0)

#define G256_RD2(slot) do { \
  const unsigned s_ = (unsigned)(slot)*16384u; \
  DSR(bf1[0], bRd + s_ + 2048u); DSR(bf1[1], bRd + s_ + 3072u); \
} while(0)

#define G256_MM(c0, bA, bB) do { \
  _Pragma("unroll") \
  for (int fr_ = 0; fr_ < 8; ++fr_) { \
    acc[fr_][(c0)]   = mfma16(af[fr_], bA, acc[fr_][(c0)]); \
    acc[fr_][(c0)+1] = mfma16(af[fr_], bB, acc[fr_][(c0)+1]); \
  } \
} while(0)

template<int EPI>
__global__ __launch_bounds__(512, 2)
void gemm256(const short* __restrict__ A, const short* __restrict__ B,
             void* __restrict__ Cv, const float* __restrict__ bias,
             const float* __restrict__ aux,
             int M, int N, int K, int lda, int ldb, int ldc,
             long long sA, long long sB, long long sC)
{
  __shared__ __align__(16) short As[3*256*32];   // 48 KB
  __shared__ __align__(16) short Bs[3*256*32];   // 48 KB
  const int lane = threadIdx.x & 63;
  const int wave = threadIdx.x >> 6;
  const int wr = wave >> 2, wc = wave & 3;       // 2M x 4N, per-wave 128x64
  TILE_MAP(256, 256)
  const int z = blockIdx.z;
  A += (long long)z * sA;
  B += (long long)z * sB;

  const int NT = K >> 5;

  const int rr   = wave * 16 + (lane >> 2);
  const int soff = (((lane & 3) ^ ((lane >> 3) & 3)) << 3);   // elements
  const short* pA = A + (long long)(tm + rr) * lda + soff;
  const short* pB = B + (long long)(tn + rr) * ldb + soff;
  const long long lda128 = 128LL * lda;
  const long long ldb128 = 128LL * ldb;

  auto stA = [&](int t, int slot) {
    const long long ko = (long long)t << 5;
    __builtin_amdgcn_global_load_lds((AS1)(pA + ko),
        (AS3)(As + slot * 8192 + wave * 512), 16, 0, 0);
    __builtin_amdgcn_global_load_lds((AS1)(pA + lda128 + ko),
        (AS3)(As + slot * 8192 + 4096 + wave * 512), 16, 0, 0);
  };
  auto stB = [&](int t, int slot) {
    const long long ko = (long long)t << 5;
    __builtin_amdgcn_global_load_lds((AS1)(pB + ko),
        (AS3)(Bs + slot * 8192 + wave * 512), 16, 0, 0);
    __builtin_amdgcn_global_load_lds((AS1)(pB + ldb128 + ko),
        (AS3)(Bs + slot * 8192 + 4096 + wave * 512), 16, 0, 0);
  };

  const unsigned asB = (unsigned)(unsigned long long)(lds_sp)As;
  const unsigned bsB = (unsigned)(unsigned long long)(lds_sp)Bs;
  const int l15 = lane & 15, l4 = lane >> 4;
  const unsigned offk = (unsigned)((l4 ^ ((l15 >> 1) & 3)) << 4);
  const unsigned aRd = asB + (unsigned)((wr * 128 + l15) * 64) + offk;
  const unsigned bRd = bsB + (unsigned)((wc * 64 + l15) * 64) + offk;

  f32x4 acc[8][4] = {};
  u32x4 af[8], bf0[2], bf1[2];

  stA(0, 0); stB(0, 0);
  stA(1 < NT ? 1 : 0, 1); stB(1 < NT ? 1 : 0, 1);
  VM4();
  BARv();

  int rd = 0;
  #pragma unroll 1
  for (int t = 0; t < NT; ++t) {
    const int st = rd + 2 >= 3 ? rd - 1 : rd + 2;   // (t+2)%3
    const int tc = t + 2 < NT ? t + 2 : NT - 1;
    G256_RD1(rd);
    G256_RD2(rd);
    stA(tc, st); stB(tc, st);
    LGKMW(2);
    PRIO1(); G256_MM(0, bf0[0], bf0[1]);
    LGKMW(0);
    G256_MM(2, bf1[0], bf1[1]); PRIO0();
    VM4();
    BARv();
    rd = rd + 1 >= 3 ? 0 : rd + 1;
  }

  const int row0 = tm + wr * 128 + l4 * 4;
  const int col0 = tn + wc * 64 + l15;
  #pragma unroll
  for (int fr = 0; fr < 8; ++fr)
    #pragma unroll
    for (int j = 0; j < 4; ++j)
      #pragma unroll
      for (int fc = 0; fc < 4; ++fc)
        epi_store<EPI>(Cv, bias, aux, z, sC, ldc, N,
                       row0 + fr * 16 + j, col0 + fc * 16, acc[fr][fc][j]);
}

// ---------------------------------------------------------------------------
// gemm_bn128 (round-12/13 verified): 256x128 block, per-wave 128x32, 3-slot
// rotation. QKV grid 48x16 = 768 wg = 3 full dispatch rounds.
// ---------------------------------------------------------------------------
template<int EPI>
__global__ __launch_bounds__(512, 2)
void gemm_bn128(const short* __restrict__ A, const short* __restrict__ B,
                void* __restrict__ Cv, const float* __restrict__ bias,
                const float* __restrict__ aux,
                int M, int N, int K, int lda, int ldb, int ldc,
                long long sA, long long sB, long long sC)
{
  __shared__ __align__(16) short As[3*256*32];   // 48 KB
  __shared__ __align__(16) short Bs[3*256*32];   // 48 KB (half used)
  const int lane = threadIdx.x & 63;
  const int wave = threadIdx.x >> 6;
  const int wr = wave >> 2, wc = wave & 3;       // per-wave 128 x 32
  TILE_MAP(256, 128)
  const int z = blockIdx.z;
  A += (long long)z * sA;
  B += (long long)z * sB;

  const int NT = K >> 5;

  const int rr   = wave * 16 + (lane >> 2);
  const int soff = (((lane & 3) ^ ((lane >> 3) & 3)) << 3);
  const short* pA = A + (long long)(tm + rr) * lda + soff;
  const short* pB = B + (long long)(tn + rr) * ldb + soff;
  const long long lda128 = 128LL * lda;

  auto stage = [&](int t, int slot) {
    const long long ko = (long long)t << 5;
    __builtin_amdgcn_global_load_lds((AS1)(pA + ko),
        (AS3)(As + slot * 8192 + wave * 512), 16, 0, 0);
    __builtin_amdgcn_global_load_lds((AS1)(pA + lda128 + ko),
        (AS3)(As + slot * 8192 + 4096 + wave * 512), 16, 0, 0);
    __builtin_amdgcn_global_load_lds((AS1)(pB + ko),
        (AS3)(Bs + slot * 8192 + wave * 512), 16, 0, 0);
  };

  const unsigned asB = (unsigned)(unsigned long long)(lds_sp)As;
  const unsigned bsB = (unsigned)(unsigned long long)(lds_sp)Bs;
  const int l15 = lane & 15, l4 = lane >> 4;
  const unsigned offk = (unsigned)((l4 ^ ((l15 >> 1) & 3)) << 4);
  const unsigned aRd = asB + (unsigned)((wr * 128 + l15) * 64) + offk;
  const unsigned bRd = bsB + (unsigned)((wc * 32 + l15) * 64) + offk;

  f32x4 acc[8][2] = {};
  u32x4 af[8], bf[2];

  stage(0, 0);
  stage(1 < NT ? 1 : 0, 1);
  VM3();
  BARv();

  int rd = 0;
  #pragma unroll 1
  for (int t = 0; t < NT; ++t) {
    const int st = rd + 2 >= 3 ? rd - 1 : rd + 2;
    const int tc = t + 2 < NT ? t + 2 : NT - 1;
    {
      const unsigned s_ = (unsigned)rd * 16384u;
      DSR(bf[0], bRd + s_);          DSR(bf[1], bRd + s_ + 1024u);
      DSR(af[0], aRd + s_);          DSR(af[1], aRd + s_ + 1024u);
      DSR(af[2], aRd + s_ + 2048u);  DSR(af[3], aRd + s_ + 3072u);
      DSR(af[4], aRd + s_ + 4096u);  DSR(af[5], aRd + s_ + 5120u);
      DSR(af[6], aRd + s_ + 6144u);  DSR(af[7], aRd + s_ + 7168u);
    }
    stage(tc, st);
    LGKMW(4);
    PRIO1();
    #pragma unroll
    for (int fr = 0; fr < 4; ++fr) {
      acc[fr][0] = mfma16(af[fr], bf[0], acc[fr][0]);
      acc[fr][1] = mfma16(af[fr], bf[1], acc[fr][1]);
    }
    LGKMW(0);
    #pragma unroll
    for (int fr = 4; fr < 8; ++fr) {
      acc[fr][0] = mfma16(af[fr], bf[0], acc[fr][0]);
      acc[fr][1] = mfma16(af[fr], bf[1], acc[fr][1]);
    }
    PRIO0();
    VM3();
    BARv();
    rd = rd + 1 >= 3 ? 0 : rd + 1;
  }

  const int row0 = tm + wr * 128 + l4 * 4;
  const int col0 = tn + wc * 32 + l15;
  #pragma unroll
  for (int fr = 0; fr < 8; ++fr)
    #pragma unroll
    for (int j = 0; j < 4; ++j)
      #pragma unroll
      for (int fc = 0; fc < 2; ++fc)
        epi_store<EPI>(Cv, bias, aux, z, sC, ldc, N,
                       row0 + fr * 16 + j, col0 + fc * 16, acc[fr][fc][j]);
}

// ---------------------------------------------------------------------------
// gemm_hi (round-8/13 verified): 128x256 tile, BK=32, 3-slot rotation,
// 72KB LDS -> 2 wg/CU. CZ: 0 dense | 1 causal tile-skip | 2 causal K-cap.
// ---------------------------------------------------------------------------
#define HRD2(slot) do { \
  const unsigned a_ = aBaseH + (unsigned)(slot)*8192u; \
  const unsigned b_ = bBaseH + (unsigned)(slot)*16384u; \
  DSR(bf[0], b_ + offk);          DSR(bf[1], b_ + 1024u + offk); \
  DSR(bf[2], b_ + 2048u + offk);  DSR(bf[3], b_ + 3072u + offk); \
  DSR(af[0], a_ + offk);          DSR(af[1], a_ + 1024u + offk); \
  DSR(af[2], a_ + 2048u + offk);  DSR(af[3], a_ + 3072u + offk); \
} while(0)

#define HROW(mi) do { \
  _Pragma("unroll") \
  for (int ni = 0; ni < 4; ++ni) \
    acc[mi][ni] = mfma16(af[mi], bf[ni], acc[mi][ni]); \
} while(0)

template<int EPI, int CZ>
__global__ __launch_bounds__(512, 4)
void gemm_hi(const short* __restrict__ A, const short* __restrict__ B,
             void* __restrict__ Cv, const float* __restrict__ bias,
             const float* __restrict__ aux,
             int M, int N, int K, int lda, int ldb, int ldc,
             long long sA, long long sB, long long sC)
{
  __shared__ __align__(16) short As[3*128*32];   // 24 KB
  __shared__ __align__(16) short Bs[3*256*32];   // 48 KB
  const int lane = threadIdx.x & 63;
  const int wave = threadIdx.x >> 6;
  const int wr = wave >> 2, wc = wave & 3;
  TILE_MAP(128, 256)
  if (CZ == 1 && tn >= tm + 128) return;
  const int z = blockIdx.z;
  A += (long long)z * sA;
  B += (long long)z * sB;

  const int NT = (CZ == 2) ? ((tm + 128) >> 5) : (K >> 5);

  const int rr   = wave * 16 + (lane >> 2);
  const int soff = (((lane & 3) ^ ((lane >> 3) & 3)) << 3);
  const short* pA = A + (long long)(tm + rr) * lda + soff;
  const short* pB = B + (long long)(tn + rr) * ldb + soff;
  const long long ldb128 = 128LL * ldb;

  auto stage = [&](int t, int slot) {
    const long long ko = (long long)t << 5;
    __builtin_amdgcn_global_load_lds((AS1)(pA + ko),
        (AS3)(As + slot * 4096 + wave * 512), 16, 0, 0);
    __builtin_amdgcn_global_load_lds((AS1)(pB + ko),
        (AS3)(Bs + slot * 8192 + wave * 512), 16, 0, 0);
    __builtin_amdgcn_global_load_lds((AS1)(pB + ldb128 + ko),
        (AS3)(Bs + slot * 8192 + 4096 + wave * 512), 16, 0, 0);
  };

  const unsigned asB = (unsigned)(unsigned long long)(lds_sp)As;
  const unsigned bsB = (unsigned)(unsigned long long)(lds_sp)Bs;
  const int l15 = lane & 15, l4 = lane >> 4;
  const unsigned offk  = (unsigned)((l4 ^ ((l15 >> 1) & 3)) << 4);
  const unsigned aBaseH = asB + (unsigned)(wr * 4096 + l15 * 64);
  const unsigned bBaseH = bsB + (unsigned)(wc * 4096 + l15 * 64);

  f32x4 acc[4][4] = {};
  u32x4 af[4], bf[4];

  stage(0, 0);
  stage(1 < NT ? 1 : 0, 1);
  VM3();
  BARv();

  int rd = 0;
  #pragma unroll 1
  for (int t = 0; t < NT; ++t) {
    const int st = rd + 2 >= 3 ? rd - 1 : rd + 2;
    const int tc = t + 2 < NT ? t + 2 : NT - 1;
    HRD2(rd);
    stage(tc, st);
    LGKMW(3);
    PRIO1(); HROW(0);
    LGKMW(2); HROW(1);
    LGKMW(1); HROW(2);
    LGKMW(0); HROW(3); PRIO0();
    VM3();
    BARv();
    rd = rd + 1 >= 3 ? 0 : rd + 1;
  }

  const int row0 = tm + wr * 64 + l4 * 4;
  const int col0 = tn + wc * 64 + l15;
  #pragma unroll
  for (int mi = 0; mi < 4; ++mi)
    #pragma unroll
    for (int j = 0; j < 4; ++j)
      #pragma unroll
      for (int ni = 0; ni < 4; ++ni)
        epi_store<EPI>(Cv, bias, aux, z, sC, ldc, N,
                       row0 + mi * 16 + j, col0 + ni * 16, acc[mi][ni][j]);
}

// ---------------------------------------------------------------------------
// LayerNorm: out_bf16[row] = LN(x[row] (+ res)) * g + b
// hasres: 0 none | 1 res f32 | 2 res bf16
// ---------------------------------------------------------------------------
__global__ __launch_bounds__(256)
void ln_kernel(const float* __restrict__ x, const void* __restrict__ res,
               const float* __restrict__ g, const float* __restrict__ b,
               short* __restrict__ out, int hasres)
{
  const int row = blockIdx.x;
  const int tid = threadIdx.x;
  const float4* X = (const float4*)x + (long long)row * 512;
  float4 v0 = X[tid], v1 = X[tid + 256];
  if (hasres == 1) {
    const float4* R = (const float4*)res + (long long)row * 512;
    float4 r0 = R[tid], r1 = R[tid + 256];
    v0.x += r0.x; v0.y += r0.y; v0.z += r0.z; v0.w += r0.w;
    v1.x += r1.x; v1.y += r1.y; v1.z += r1.z; v1.w += r1.w;
  } else if (hasres == 2) {
    const short* R = (const short*)res + (long long)row * 2048;
    s16x4 r0 = *(const s16x4*)&R[tid * 4];
    s16x4 r1 = *(const s16x4*)&R[1024 + tid * 4];
    v0.x += bf2f(r0[0]); v0.y += bf2f(r0[1]); v0.z += bf2f(r0[2]); v0.w += bf2f(r0[3]);
    v1.x += bf2f(r1[0]); v1.y += bf2f(r1[1]); v1.z += bf2f(r1[2]); v1.w += bf2f(r1[3]);
  }
  float s1 = v0.x + v0.y + v0.z + v0.w + v1.x + v1.y + v1.z + v1.w;
  float s2 = v0.x*v0.x + v0.y*v0.y + v0.z*v0.z + v0.w*v0.w
           + v1.x*v1.x + v1.y*v1.y + v1.z*v1.z + v1.w*v1.w;
  #pragma unroll
  for (int o = 32; o > 0; o >>= 1) { s1 += __shfl_xor(s1, o); s2 += __shfl_xor(s2, o); }
  __shared__ float red[8];
  if ((tid & 63) == 0) { red[tid >> 6] = s1; red[4 + (tid >> 6)] = s2; }
  __syncthreads();
  s1 = red[0] + red[1] + red[2] + red[3];
  s2 = red[4] + red[5] + red[6] + red[7];
  const float mean = s1 * (1.0f / 2048.0f);
  const float var  = s2 * (1.0f / 2048.0f) - mean * mean;
  const float rstd = rsqrtf(var + 1e-5f);
  const float4* G  = (const float4*)g;
  const float4* Bb = (const float4*)b;
  float4 g0 = G[tid], g1 = G[tid + 256], b0 = Bb[tid], b1 = Bb[tid + 256];
  s16x4 o0, o1;
  o0[0] = f2bf((v0.x - mean) * rstd * g0.x + b0.x);
  o0[1] = f2bf((v0.y - mean) * rstd * g0.y + b0.y);
  o0[2] = f2bf((v0.z - mean) * rstd * g0.z + b0.z);
  o0[3] = f2bf((v0.w - mean) * rstd * g0.w + b0.w);
  o1[0] = f2bf((v1.x - mean) * rstd * g1.x + b1.x);
  o1[1] = f2bf((v1.y - mean) * rstd * g1.y + b1.y);
  o1[2] = f2bf((v1.z - mean) * rstd * g1.z + b1.z);
  o1[3] = f2bf((v1.w - mean) * rstd * g1.w + b1.w);
  *(s16x4*)&out[(long long)row * 2048 + tid * 4]        = o0;
  *(s16x4*)&out[(long long)row * 2048 + 1024 + tid * 4] = o1;
}

// ---------------------------------------------------------------------------
// Causal in-place softmax over bf16 rows (round-13 verified)
// ---------------------------------------------------------------------------
__global__ __launch_bounds__(256)
void softmax_causal_kernel(short* __restrict__ probs)
{
  const long long row = blockIdx.x;
  const int q  = blockIdx.x & (SEQ_ - 1);
  const int tid = threadIdx.x;
  short* P = probs + row * 2048 + tid * 8;
  const int kbase = tid * 8;
  s16x8 in = *(const s16x8*)P;
  float a[8];
  #pragma unroll
  for (int i = 0; i < 8; ++i) a[i] = bf2f(in[i]);
  float mx = -1e30f;
  #pragma unroll
  for (int i = 0; i < 8; ++i) {
    const float av = (kbase + i <= q) ? a[i] : -1e30f;
    mx = fmaxf(mx, av);
  }
  #pragma unroll
  for (int o = 32; o > 0; o >>= 1) mx = fmaxf(mx, __shfl_xor(mx, o));
  __shared__ float red[8];
  if ((tid & 63) == 0) red[tid >> 6] = mx;
  __syncthreads();
  mx = fmaxf(fmaxf(red[0], red[1]), fmaxf(red[2], red[3]));
  float e[8], sum = 0.f;
  #pragma unroll
  for (int i = 0; i < 8; ++i) {
    e[i] = (kbase + i <= q) ? __expf(a[i] - mx) : 0.f;
    sum += e[i];
  }
  #pragma unroll
  for (int o = 32; o > 0; o >>= 1) sum += __shfl_xor(sum, o);
  if ((tid & 63) == 0) red[4 + (tid >> 6)] = sum;
  __syncthreads();
  sum = red[4] + red[5] + red[6] + red[7];
  const float inv = 1.0f / sum;
  s16x8 o;
  #pragma unroll
  for (int i = 0; i < 8; ++i) o[i] = f2bf(e[i] * inv);
  *(s16x8*)P = o;
}

// ---------------------------------------------------------------------------
// fp32 (R,C) -> bf16 (C,R) transpose-convert, 64x64 tiles, float4 loads.
// Batched 3-input variant for wq/wk/wv.
// ---------------------------------------------------------------------------
__device__ __forceinline__ void cvt_t64_body(const float* in, short* out, int R, int C)
{
  __shared__ float t[64][69];
  const int r0 = blockIdx.y << 6, c0 = blockIdx.x << 6;
  const int tx = threadIdx.x & 15, ty = threadIdx.x >> 4;
  #pragma unroll
  for (int p = 0; p < 4; ++p) {
    const int r = ty + p * 16;
    float4 v = *(const float4*)&in[(long long)(r0 + r) * C + c0 + tx * 4];
    t[r][tx*4+0] = v.x; t[r][tx*4+1] = v.y; t[r][tx*4+2] = v.z; t[r][tx*4+3] = v.w;
  }
  __syncthreads();
  #pragma unroll
  for (int p = 0; p < 4; ++p) {
    const int oc = ty + p * 16;
    s16x4 o;
    o[0] = f2bf(t[tx*4+0][oc]); o[1] = f2bf(t[tx*4+1][oc]);
    o[2] = f2bf(t[tx*4+2][oc]); o[3] = f2bf(t[tx*4+3][oc]);
    *(s16x4*)&out[(long long)(c0 + oc) * R + r0 + tx * 4] = o;
  }
}

__global__ __launch_bounds__(256)
void cvt_transpose64(const float* __restrict__ in, short* __restrict__ out,
                     int R, int C)
{ cvt_t64_body(in, out, R, C); }

__global__ __launch_bounds__(256)
void cvt3_transpose64(const float* __restrict__ a, const float* __restrict__ b,
                      const float* __restrict__ c, short* __restrict__ out)
{
  const int z = blockIdx.z;
  const float* in = z == 0 ? a : (z == 1 ? b : c);
  cvt_t64_body(in, out + (size_t)z * DIM_ * DIM_, DIM_, DIM_);
}

// bf16 strided (z,R,C) -> (z,C,R) transpose (V)
__global__ __launch_bounds__(256)
void transpose_bf16_kernel(const short* __restrict__ in, short* __restrict__ out,
                           int ldin, int ldout, long long sin_, long long sout_)
{
  __shared__ short t[32][33];
  in  += (long long)blockIdx.z * sin_;
  out += (long long)blockIdx.z * sout_;
  const int tx = threadIdx.x & 31, ty = threadIdx.x >> 5;
  const int r0 = blockIdx.y << 5, c0 = blockIdx.x << 5;
  #pragma unroll
  for (int i = 0; i < 32; i += 8)
    t[ty + i][tx] = in[(long long)(r0 + ty + i) * ldin + c0 + tx];
  __syncthreads();
  #pragma unroll
  for (int i = 0; i < 32; i += 8)
    out[(long long)(c0 + ty + i) * ldout + r0 + tx] = t[tx][ty + i];
}

__global__ __launch_bounds__(256)
void concat_bias_kernel(const float* a, const float* b, const float* c, float* o)
{
  const int i = blockIdx.x * 256 + threadIdx.x;   // 6144
  o[i] = i < 2048 ? a[i] : (i < 4096 ? b[i - 2048] : c[i - 4096]);
}

// ---------------------------------------------------------------------------
extern "C" void kernel_launch(void* const* d_in, const int* in_sizes, int n_in,
                              void* d_out, int out_size, void* d_ws, size_t ws_size,
                              hipStream_t stream)
{
  const float* x    = (const float*)d_in[0];
  const float* mask = (const float*)d_in[1];
  const float* wq   = (const float*)d_in[4];
  const float* bq   = (const float*)d_in[5];
  const float* wk   = (const float*)d_in[6];
  const float* bk   = (const float*)d_in[7];
  const float* wv   = (const float*)d_in[8];
  const float* bv   = (const float*)d_in[9];
  const float* g1   = (const float*)d_in[10];
  const float* b1   = (const float*)d_in[11];
  const float* g2   = (const float*)d_in[12];
  const float* b2   = (const float*)d_in[13];
  const float* w1   = (const float*)d_in[14];
  const float* bw1  = (const float*)d_in[15];
  const float* w2   = (const float*)d_in[16];
  const float* bw2  = (const float*)d_in[17];
  float* out = (float*)d_out;

  char* p = (char*)d_ws;
  auto take = [&](size_t bytes) { char* r = p; p += (bytes + 255) & ~(size_t)255; return r; };
  short* wqkvT = (short*)take((size_t)3 * DIM_ * DIM_ * 2);  // [6144][2048] bf16
  short* w1T   = (short*)take((size_t)DIM_ * HID_ * 2);      // [8192][2048]
  short* w2T   = (short*)take((size_t)HID_ * DIM_ * 2);      // [2048][8192]
  short* h_bf  = (short*)take((size_t)TOK_ * DIM_ * 2);      // reused as h2
  short* qkv   = (short*)take((size_t)TOK_ * 3 * DIM_ * 2);  // [4096][6144]
  short* vT    = (short*)take((size_t)BATCH_ * DIM_ * SEQ_ * 2);
  short* attno = (short*)take((size_t)TOK_ * DIM_ * 2);      // bf16
  short* attn  = (short*)take((size_t)BATCH_ * SEQ_ * SEQ_ * 2);
  float* cbias = (float*)take((size_t)3 * DIM_ * 4);
  short* ffn1  = qkv;          // alias over qkv+vT (dead after PV)
  short* h2    = h_bf;         // alias (h dead after QKV)

  const dim3 blk(256), gblk(512);
  // weight convert+transpose (batched QKV + w1 + w2)
  cvt3_transpose64<<<dim3(DIM_/64, DIM_/64, 3), blk, 0, stream>>>(wq, wk, wv, wqkvT);
  cvt_transpose64<<<dim3(HID_/64, DIM_/64), blk, 0, stream>>>(w1, w1T, DIM_, HID_);
  cvt_transpose64<<<dim3(DIM_/64, HID_/64), blk, 0, stream>>>(w2, w2T, HID_, DIM_);
  concat_bias_kernel<<<24, blk, 0, stream>>>(bq, bk, bv, cbias);
  // LN1
  ln_kernel<<<TOK_, blk, 0, stream>>>(x, nullptr, g1, b1, h_bf, 0);
  // fused QKV (gemm_bn128 3-slot, 768 wg = 3 full rounds)
  gemm_bn128<0><<<dim3(6144/128, TOK_/256, 1), gblk, 0, stream>>>(
      h_bf, wqkvT, qkv, cbias, nullptr, TOK_, 6144, DIM_, DIM_, DIM_, 6144, 0, 0, 0);
  // scores (scale+mask fused, causal skip) -> bf16 attn
  gemm_hi<4,1><<<dim3(SEQ_/256, SEQ_/128, BATCH_), gblk, 0, stream>>>(
      qkv, qkv + DIM_, attn, nullptr, mask, SEQ_, SEQ_, DIM_, 6144, 6144, SEQ_,
      (long long)SEQ_ * 6144, (long long)SEQ_ * 6144, (long long)SEQ_ * SEQ_);
  // causal in-place softmax
  softmax_causal_kernel<<<BATCH_ * SEQ_, blk, 0, stream>>>(attn);
  // V transpose: (B,S,D) strided in qkv -> vT (B,D,S)
  transpose_bf16_kernel<<<dim3(DIM_/32, SEQ_/32, BATCH_), blk, 0, stream>>>(
      qkv + 2*DIM_, vT, 6144, SEQ_, (long long)SEQ_ * 6144, (long long)DIM_ * SEQ_);
  // attn_out = probs @ V (causal K-cap) -> bf16
  gemm_hi<5,2><<<dim3(DIM_/256, SEQ_/128, BATCH_), gblk, 0, stream>>>(
      attn, vT, attno, nullptr, nullptr, SEQ_, DIM_, SEQ_, SEQ_, SEQ_, DIM_,
      (long long)SEQ_ * SEQ_, (long long)DIM_ * SEQ_, (long long)SEQ_ * DIM_);
  // LN2 over x + attn_out(bf16)
  ln_kernel<<<TOK_, blk, 0, stream>>>(x, attno, g2, b2, h2, 2);
  // FFN1 (gemm256 3-slot): gelu(h2 @ w1 + b1) -> bf16
  gemm256<2><<<dim3(HID_/256, TOK_/256, 1), gblk, 0, stream>>>(
      h2, w1T, ffn1, bw1, nullptr, TOK_, HID_, DIM_, DIM_, DIM_, HID_, 0, 0, 0);
  // FFN2 (gemm_hi 3-slot, 2 wg/CU): x + (ffn1 @ w2 + b2) -> fp32 d_out
  gemm_hi<3,0><<<dim3(DIM_/256, TOK_/128, 1), gblk, 0, stream>>>(
      ffn1, w2T, out, bw2, x, TOK_, DIM_, HID_, HID_, HID_, DIM_, 0, 0, 0);
}

// Round 18
// 601.182 us; speedup vs baseline: 1.0377x; 1.0132x over previous
//
#include <hip/hip_runtime.h>
#include <math.h>

#define DIM_ 2048
#define HID_ 8192
#define SEQ_ 2048
#define BATCH_ 2
#define TOK_ (BATCH_*SEQ_)

typedef __attribute__((ext_vector_type(4))) float f32x4;
typedef __attribute__((ext_vector_type(8))) __bf16 bf16x8;
typedef __attribute__((ext_vector_type(4))) unsigned int u32x4;
typedef __attribute__((ext_vector_type(4))) short s16x4;
typedef __attribute__((ext_vector_type(8))) short s16x8;
typedef __attribute__((address_space(3))) short* lds_sp;

__device__ __forceinline__ short f2bf(float f) {
  union { float f; unsigned u; } v; v.f = f;
  unsigned r = v.u + 0x7FFFu + ((v.u >> 16) & 1u);
  return (short)(r >> 16);
}
__device__ __forceinline__ float bf2f(short s) {
  union { unsigned u; float f; } v; v.u = ((unsigned)(unsigned short)s) << 16;
  return v.f;
}

__device__ __forceinline__ f32x4 mfma16(u32x4 a, u32x4 b, f32x4 c) {
  return __builtin_amdgcn_mfma_f32_16x16x32_bf16(
      __builtin_bit_cast(bf16x8, a), __builtin_bit_cast(bf16x8, b), c, 0, 0, 0);
}

#define DSR(dst, addr) asm volatile("ds_read_b128 %0, %1" : "=v"(dst) : "v"(addr))
#define BARv()  __builtin_amdgcn_s_barrier()
#define LGKMW(n) do { asm volatile("s_waitcnt lgkmcnt(" #n ")" ::: "memory"); \
                      __builtin_amdgcn_sched_barrier(0); } while(0)
#define VM3()   asm volatile("s_waitcnt vmcnt(3)" ::: "memory")
#define VM4()   asm volatile("s_waitcnt vmcnt(4)" ::: "memory")
#define PRIO1() __builtin_amdgcn_s_setprio(1)
#define PRIO0() __builtin_amdgcn_s_setprio(0)
#define AS1 const __attribute__((address_space(1))) void*
#define AS3 __attribute__((address_space(3))) void*

// XCD-chunk + 4-column-group tile mapping (bijective; needs nwg%8==0, gx%4==0)
#define TILE_MAP(BM, BN) \
  const int nwg  = gridDim.x * gridDim.y; \
  const int orig = blockIdx.y * gridDim.x + blockIdx.x; \
  const int wgid = (orig & 7) * (nwg >> 3) + (orig >> 3); \
  const int gy4  = (int)gridDim.y << 2; \
  const int rem  = wgid % gy4; \
  const int tn   = ((wgid / gy4) * 4 + (rem & 3)) * (BN); \
  const int tm   = (rem >> 2) * (BM);

// EPI: 0 bias->bf16 | 1 raw f32 | 2 bias+GELU->bf16 | 3 bias+aux->f32
//      4 scale+mask->bf16 (aux = mask) | 5 raw->bf16
template<int EPI>
__device__ __forceinline__ void epi_store(void* Cv, const float* bias, const float* aux,
                                          int z, long long sC, int ldc, int N,
                                          int row, int col, float v)
{
  if (EPI == 1) {
    ((float*)Cv + (long long)z * sC)[(long long)row * ldc + col] = v;
  } else if (EPI == 0) {
    v += bias[col];
    ((short*)Cv + (long long)z * sC)[(long long)row * ldc + col] = f2bf(v);
  } else if (EPI == 2) {
    v += bias[col];
    v = 0.5f * v * (1.0f + erff(v * 0.70710678118654752f));
    ((short*)Cv + (long long)z * sC)[(long long)row * ldc + col] = f2bf(v);
  } else if (EPI == 3) {
    v += bias[col] + aux[(long long)row * ldc + col];
    ((float*)Cv + (long long)z * sC)[(long long)row * ldc + col] = v;
  } else if (EPI == 4) {
    v = v * 0.022097086912079608f + aux[(long long)row * ldc + col];
    ((short*)Cv + (long long)z * sC)[(long long)row * ldc + col] = f2bf(v);
  } else { // 5
    ((short*)Cv + (long long)z * sC)[(long long)row * ldc + col] = f2bf(v);
  }
}

// ---------------------------------------------------------------------------
// gemm_bn128 (round-12/13 verified): 256x128 block, per-wave 128x32, 3-slot
// rotation. QKV grid 48x16 = 768 wg = 3 full dispatch rounds.
// ---------------------------------------------------------------------------
template<int EPI>
__global__ __launch_bounds__(512, 2)
void gemm_bn128(const short* __restrict__ A, const short* __restrict__ B,
                void* __restrict__ Cv, const float* __restrict__ bias,
                const float* __restrict__ aux,
                int M, int N, int K, int lda, int ldb, int ldc,
                long long sA, long long sB, long long sC)
{
  __shared__ __align__(16) short As[3*256*32];   // 48 KB
  __shared__ __align__(16) short Bs[3*256*32];   // 48 KB (half used)
  const int lane = threadIdx.x & 63;
  const int wave = threadIdx.x >> 6;
  const int wr = wave >> 2, wc = wave & 3;       // per-wave 128 x 32
  TILE_MAP(256, 128)
  const int z = blockIdx.z;
  A += (long long)z * sA;
  B += (long long)z * sB;

  const int NT = K >> 5;

  const int rr   = wave * 16 + (lane >> 2);
  const int soff = (((lane & 3) ^ ((lane >> 3) & 3)) << 3);
  const short* pA = A + (long long)(tm + rr) * lda + soff;
  const short* pB = B + (long long)(tn + rr) * ldb + soff;
  const long long lda128 = 128LL * lda;

  auto stage = [&](int t, int slot) {
    const long long ko = (long long)t << 5;
    __builtin_amdgcn_global_load_lds((AS1)(pA + ko),
        (AS3)(As + slot * 8192 + wave * 512), 16, 0, 0);
    __builtin_amdgcn_global_load_lds((AS1)(pA + lda128 + ko),
        (AS3)(As + slot * 8192 + 4096 + wave * 512), 16, 0, 0);
    __builtin_amdgcn_global_load_lds((AS1)(pB + ko),
        (AS3)(Bs + slot * 8192 + wave * 512), 16, 0, 0);
  };

  const unsigned asB = (unsigned)(unsigned long long)(lds_sp)As;
  const unsigned bsB = (unsigned)(unsigned long long)(lds_sp)Bs;
  const int l15 = lane & 15, l4 = lane >> 4;
  const unsigned offk = (unsigned)((l4 ^ ((l15 >> 1) & 3)) << 4);
  const unsigned aRd = asB + (unsigned)((wr * 128 + l15) * 64) + offk;
  const unsigned bRd = bsB + (unsigned)((wc * 32 + l15) * 64) + offk;

  f32x4 acc[8][2] = {};
  u32x4 af[8], bf[2];

  stage(0, 0);
  stage(1 < NT ? 1 : 0, 1);
  VM3();
  BARv();

  int rd = 0;
  #pragma unroll 1
  for (int t = 0; t < NT; ++t) {
    const int st = rd + 2 >= 3 ? rd - 1 : rd + 2;
    const int tc = t + 2 < NT ? t + 2 : NT - 1;
    {
      const unsigned s_ = (unsigned)rd * 16384u;
      DSR(bf[0], bRd + s_);          DSR(bf[1], bRd + s_ + 1024u);
      DSR(af[0], aRd + s_);          DSR(af[1], aRd + s_ + 1024u);
      DSR(af[2], aRd + s_ + 2048u);  DSR(af[3], aRd + s_ + 3072u);
      DSR(af[4], aRd + s_ + 4096u);  DSR(af[5], aRd + s_ + 5120u);
      DSR(af[6], aRd + s_ + 6144u);  DSR(af[7], aRd + s_ + 7168u);
    }
    stage(tc, st);
    LGKMW(4);
    PRIO1();
    #pragma unroll
    for (int fr = 0; fr < 4; ++fr) {
      acc[fr][0] = mfma16(af[fr], bf[0], acc[fr][0]);
      acc[fr][1] = mfma16(af[fr], bf[1], acc[fr][1]);
    }
    LGKMW(0);
    #pragma unroll
    for (int fr = 4; fr < 8; ++fr) {
      acc[fr][0] = mfma16(af[fr], bf[0], acc[fr][0]);
      acc[fr][1] = mfma16(af[fr], bf[1], acc[fr][1]);
    }
    PRIO0();
    VM3();
    BARv();
    rd = rd + 1 >= 3 ? 0 : rd + 1;
  }

  const int row0 = tm + wr * 128 + l4 * 4;
  const int col0 = tn + wc * 32 + l15;
  #pragma unroll
  for (int fr = 0; fr < 8; ++fr)
    #pragma unroll
    for (int j = 0; j < 4; ++j)
      #pragma unroll
      for (int fc = 0; fc < 2; ++fc)
        epi_store<EPI>(Cv, bias, aux, z, sC, ldc, N,
                       row0 + fr * 16 + j, col0 + fc * 16, acc[fr][fc][j]);
}

// ---------------------------------------------------------------------------
// gemm_hi (round-8/13 verified, ~870 TF): 128x256 tile, BK=32, 3-slot
// rotation, 72KB LDS -> 2 wg/CU. CZ: 0 dense | 1 causal skip | 2 causal K-cap
// ---------------------------------------------------------------------------
#define HRD2(slot) do { \
  const unsigned a_ = aBaseH + (unsigned)(slot)*8192u; \
  const unsigned b_ = bBaseH + (unsigned)(slot)*16384u; \
  DSR(bf[0], b_ + offk);          DSR(bf[1], b_ + 1024u + offk); \
  DSR(bf[2], b_ + 2048u + offk);  DSR(bf[3], b_ + 3072u + offk); \
  DSR(af[0], a_ + offk);          DSR(af[1], a_ + 1024u + offk); \
  DSR(af[2], a_ + 2048u + offk);  DSR(af[3], a_ + 3072u + offk); \
} while(0)

#define HROW(mi) do { \
  _Pragma("unroll") \
  for (int ni = 0; ni < 4; ++ni) \
    acc[mi][ni] = mfma16(af[mi], bf[ni], acc[mi][ni]); \
} while(0)

template<int EPI, int CZ>
__global__ __launch_bounds__(512, 4)
void gemm_hi(const short* __restrict__ A, const short* __restrict__ B,
             void* __restrict__ Cv, const float* __restrict__ bias,
             const float* __restrict__ aux,
             int M, int N, int K, int lda, int ldb, int ldc,
             long long sA, long long sB, long long sC)
{
  __shared__ __align__(16) short As[3*128*32];   // 24 KB
  __shared__ __align__(16) short Bs[3*256*32];   // 48 KB
  const int lane = threadIdx.x & 63;
  const int wave = threadIdx.x >> 6;
  const int wr = wave >> 2, wc = wave & 3;
  TILE_MAP(128, 256)
  if (CZ == 1 && tn >= tm + 128) return;
  const int z = blockIdx.z;
  A += (long long)z * sA;
  B += (long long)z * sB;

  const int NT = (CZ == 2) ? ((tm + 128) >> 5) : (K >> 5);

  const int rr   = wave * 16 + (lane >> 2);
  const int soff = (((lane & 3) ^ ((lane >> 3) & 3)) << 3);
  const short* pA = A + (long long)(tm + rr) * lda + soff;
  const short* pB = B + (long long)(tn + rr) * ldb + soff;
  const long long ldb128 = 128LL * ldb;

  auto stage = [&](int t, int slot) {
    const long long ko = (long long)t << 5;
    __builtin_amdgcn_global_load_lds((AS1)(pA + ko),
        (AS3)(As + slot * 4096 + wave * 512), 16, 0, 0);
    __builtin_amdgcn_global_load_lds((AS1)(pB + ko),
        (AS3)(Bs + slot * 8192 + wave * 512), 16, 0, 0);
    __builtin_amdgcn_global_load_lds((AS1)(pB + ldb128 + ko),
        (AS3)(Bs + slot * 8192 + 4096 + wave * 512), 16, 0, 0);
  };

  const unsigned asB = (unsigned)(unsigned long long)(lds_sp)As;
  const unsigned bsB = (unsigned)(unsigned long long)(lds_sp)Bs;
  const int l15 = lane & 15, l4 = lane >> 4;
  const unsigned offk  = (unsigned)((l4 ^ ((l15 >> 1) & 3)) << 4);
  const unsigned aBaseH = asB + (unsigned)(wr * 4096 + l15 * 64);
  const unsigned bBaseH = bsB + (unsigned)(wc * 4096 + l15 * 64);

  f32x4 acc[4][4] = {};
  u32x4 af[4], bf[4];

  stage(0, 0);
  stage(1 < NT ? 1 : 0, 1);
  VM3();
  BARv();

  int rd = 0;
  #pragma unroll 1
  for (int t = 0; t < NT; ++t) {
    const int st = rd + 2 >= 3 ? rd - 1 : rd + 2;
    const int tc = t + 2 < NT ? t + 2 : NT - 1;
    HRD2(rd);
    stage(tc, st);
    LGKMW(3);
    PRIO1(); HROW(0);
    LGKMW(2); HROW(1);
    LGKMW(1); HROW(2);
    LGKMW(0); HROW(3); PRIO0();
    VM3();
    BARv();
    rd = rd + 1 >= 3 ? 0 : rd + 1;
  }

  const int row0 = tm + wr * 64 + l4 * 4;
  const int col0 = tn + wc * 64 + l15;
  #pragma unroll
  for (int mi = 0; mi < 4; ++mi)
    #pragma unroll
    for (int j = 0; j < 4; ++j)
      #pragma unroll
      for (int ni = 0; ni < 4; ++ni)
        epi_store<EPI>(Cv, bias, aux, z, sC, ldc, N,
                       row0 + mi * 16 + j, col0 + ni * 16, acc[mi][ni][j]);
}

// ---------------------------------------------------------------------------
// LayerNorm: out_bf16[row] = LN(x[row] (+ res)) * g + b
// hasres: 0 none | 1 res f32 | 2 res bf16
// ---------------------------------------------------------------------------
__global__ __launch_bounds__(256)
void ln_kernel(const float* __restrict__ x, const void* __restrict__ res,
               const float* __restrict__ g, const float* __restrict__ b,
               short* __restrict__ out, int hasres)
{
  const int row = blockIdx.x;
  const int tid = threadIdx.x;
  const float4* X = (const float4*)x + (long long)row * 512;
  float4 v0 = X[tid], v1 = X[tid + 256];
  if (hasres == 1) {
    const float4* R = (const float4*)res + (long long)row * 512;
    float4 r0 = R[tid], r1 = R[tid + 256];
    v0.x += r0.x; v0.y += r0.y; v0.z += r0.z; v0.w += r0.w;
    v1.x += r1.x; v1.y += r1.y; v1.z += r1.z; v1.w += r1.w;
  } else if (hasres == 2) {
    const short* R = (const short*)res + (long long)row * 2048;
    s16x4 r0 = *(const s16x4*)&R[tid * 4];
    s16x4 r1 = *(const s16x4*)&R[1024 + tid * 4];
    v0.x += bf2f(r0[0]); v0.y += bf2f(r0[1]); v0.z += bf2f(r0[2]); v0.w += bf2f(r0[3]);
    v1.x += bf2f(r1[0]); v1.y += bf2f(r1[1]); v1.z += bf2f(r1[2]); v1.w += bf2f(r1[3]);
  }
  float s1 = v0.x + v0.y + v0.z + v0.w + v1.x + v1.y + v1.z + v1.w;
  float s2 = v0.x*v0.x + v0.y*v0.y + v0.z*v0.z + v0.w*v0.w
           + v1.x*v1.x + v1.y*v1.y + v1.z*v1.z + v1.w*v1.w;
  #pragma unroll
  for (int o = 32; o > 0; o >>= 1) { s1 += __shfl_xor(s1, o); s2 += __shfl_xor(s2, o); }
  __shared__ float red[8];
  if ((tid & 63) == 0) { red[tid >> 6] = s1; red[4 + (tid >> 6)] = s2; }
  __syncthreads();
  s1 = red[0] + red[1] + red[2] + red[3];
  s2 = red[4] + red[5] + red[6] + red[7];
  const float mean = s1 * (1.0f / 2048.0f);
  const float var  = s2 * (1.0f / 2048.0f) - mean * mean;
  const float rstd = rsqrtf(var + 1e-5f);
  const float4* G  = (const float4*)g;
  const float4* Bb = (const float4*)b;
  float4 g0 = G[tid], g1 = G[tid + 256], b0 = Bb[tid], b1 = Bb[tid + 256];
  s16x4 o0, o1;
  o0[0] = f2bf((v0.x - mean) * rstd * g0.x + b0.x);
  o0[1] = f2bf((v0.y - mean) * rstd * g0.y + b0.y);
  o0[2] = f2bf((v0.z - mean) * rstd * g0.z + b0.z);
  o0[3] = f2bf((v0.w - mean) * rstd * g0.w + b0.w);
  o1[0] = f2bf((v1.x - mean) * rstd * g1.x + b1.x);
  o1[1] = f2bf((v1.y - mean) * rstd * g1.y + b1.y);
  o1[2] = f2bf((v1.z - mean) * rstd * g1.z + b1.z);
  o1[3] = f2bf((v1.w - mean) * rstd * g1.w + b1.w);
  *(s16x4*)&out[(long long)row * 2048 + tid * 4]        = o0;
  *(s16x4*)&out[(long long)row * 2048 + 1024 + tid * 4] = o1;
}

// ---------------------------------------------------------------------------
// Causal in-place softmax over bf16 rows (round-13 verified)
// ---------------------------------------------------------------------------
__global__ __launch_bounds__(256)
void softmax_causal_kernel(short* __restrict__ probs)
{
  const long long row = blockIdx.x;
  const int q  = blockIdx.x & (SEQ_ - 1);
  const int tid = threadIdx.x;
  short* P = probs + row * 2048 + tid * 8;
  const int kbase = tid * 8;
  s16x8 in = *(const s16x8*)P;
  float a[8];
  #pragma unroll
  for (int i = 0; i < 8; ++i) a[i] = bf2f(in[i]);
  float mx = -1e30f;
  #pragma unroll
  for (int i = 0; i < 8; ++i) {
    const float av = (kbase + i <= q) ? a[i] : -1e30f;
    mx = fmaxf(mx, av);
  }
  #pragma unroll
  for (int o = 32; o > 0; o >>= 1) mx = fmaxf(mx, __shfl_xor(mx, o));
  __shared__ float red[8];
  if ((tid & 63) == 0) red[tid >> 6] = mx;
  __syncthreads();
  mx = fmaxf(fmaxf(red[0], red[1]), fmaxf(red[2], red[3]));
  float e[8], sum = 0.f;
  #pragma unroll
  for (int i = 0; i < 8; ++i) {
    e[i] = (kbase + i <= q) ? __expf(a[i] - mx) : 0.f;
    sum += e[i];
  }
  #pragma unroll
  for (int o = 32; o > 0; o >>= 1) sum += __shfl_xor(sum, o);
  if ((tid & 63) == 0) red[4 + (tid >> 6)] = sum;
  __syncthreads();
  sum = red[4] + red[5] + red[6] + red[7];
  const float inv = 1.0f / sum;
  s16x8 o;
  #pragma unroll
  for (int i = 0; i < 8; ++i) o[i] = f2bf(e[i] * inv);
  *(s16x8*)P = o;
}

// ---------------------------------------------------------------------------
// fp32 (R,C) -> bf16 (C,R) transpose-convert, 64x64 tiles, float4 loads.
// Batched 3-input variant for wq/wk/wv.
// ---------------------------------------------------------------------------
__device__ __forceinline__ void cvt_t64_body(const float* in, short* out, int R, int C)
{
  __shared__ float t[64][69];
  const int r0 = blockIdx.y << 6, c0 = blockIdx.x << 6;
  const int tx = threadIdx.x & 15, ty = threadIdx.x >> 4;
  #pragma unroll
  for (int p = 0; p < 4; ++p) {
    const int r = ty + p * 16;
    float4 v = *(const float4*)&in[(long long)(r0 + r) * C + c0 + tx * 4];
    t[r][tx*4+0] = v.x; t[r][tx*4+1] = v.y; t[r][tx*4+2] = v.z; t[r][tx*4+3] = v.w;
  }
  __syncthreads();
  #pragma unroll
  for (int p = 0; p < 4; ++p) {
    const int oc = ty + p * 16;
    s16x4 o;
    o[0] = f2bf(t[tx*4+0][oc]); o[1] = f2bf(t[tx*4+1][oc]);
    o[2] = f2bf(t[tx*4+2][oc]); o[3] = f2bf(t[tx*4+3][oc]);
    *(s16x4*)&out[(long long)(c0 + oc) * R + r0 + tx * 4] = o;
  }
}

__global__ __launch_bounds__(256)
void cvt_transpose64(const float* __restrict__ in, short* __restrict__ out,
                     int R, int C)
{ cvt_t64_body(in, out, R, C); }

__global__ __launch_bounds__(256)
void cvt3_transpose64(const float* __restrict__ a, const float* __restrict__ b,
                      const float* __restrict__ c, short* __restrict__ out)
{
  const int z = blockIdx.z;
  const float* in = z == 0 ? a : (z == 1 ? b : c);
  cvt_t64_body(in, out + (size_t)z * DIM_ * DIM_, DIM_, DIM_);
}

// bf16 strided (z,R,C) -> (z,C,R) transpose (V)
__global__ __launch_bounds__(256)
void transpose_bf16_kernel(const short* __restrict__ in, short* __restrict__ out,
                           int ldin, int ldout, long long sin_, long long sout_)
{
  __shared__ short t[32][33];
  in  += (long long)blockIdx.z * sin_;
  out += (long long)blockIdx.z * sout_;
  const int tx = threadIdx.x & 31, ty = threadIdx.x >> 5;
  const int r0 = blockIdx.y << 5, c0 = blockIdx.x << 5;
  #pragma unroll
  for (int i = 0; i < 32; i += 8)
    t[ty + i][tx] = in[(long long)(r0 + ty + i) * ldin + c0 + tx];
  __syncthreads();
  #pragma unroll
  for (int i = 0; i < 32; i += 8)
    out[(long long)(c0 + ty + i) * ldout + r0 + tx] = t[tx][ty + i];
}

__global__ __launch_bounds__(256)
void concat_bias_kernel(const float* a, const float* b, const float* c, float* o)
{
  const int i = blockIdx.x * 256 + threadIdx.x;   // 6144
  o[i] = i < 2048 ? a[i] : (i < 4096 ? b[i - 2048] : c[i - 4096]);
}

// ---------------------------------------------------------------------------
extern "C" void kernel_launch(void* const* d_in, const int* in_sizes, int n_in,
                              void* d_out, int out_size, void* d_ws, size_t ws_size,
                              hipStream_t stream)
{
  const float* x    = (const float*)d_in[0];
  const float* mask = (const float*)d_in[1];
  const float* wq   = (const float*)d_in[4];
  const float* bq   = (const float*)d_in[5];
  const float* wk   = (const float*)d_in[6];
  const float* bk   = (const float*)d_in[7];
  const float* wv   = (const float*)d_in[8];
  const float* bv   = (const float*)d_in[9];
  const float* g1   = (const float*)d_in[10];
  const float* b1   = (const float*)d_in[11];
  const float* g2   = (const float*)d_in[12];
  const float* b2   = (const float*)d_in[13];
  const float* w1   = (const float*)d_in[14];
  const float* bw1  = (const float*)d_in[15];
  const float* w2   = (const float*)d_in[16];
  const float* bw2  = (const float*)d_in[17];
  float* out = (float*)d_out;

  char* p = (char*)d_ws;
  auto take = [&](size_t bytes) { char* r = p; p += (bytes + 255) & ~(size_t)255; return r; };
  short* wqkvT = (short*)take((size_t)3 * DIM_ * DIM_ * 2);  // [6144][2048] bf16
  short* w1T   = (short*)take((size_t)DIM_ * HID_ * 2);      // [8192][2048]
  short* w2T   = (short*)take((size_t)HID_ * DIM_ * 2);      // [2048][8192]
  short* h_bf  = (short*)take((size_t)TOK_ * DIM_ * 2);      // reused as h2
  short* qkv   = (short*)take((size_t)TOK_ * 3 * DIM_ * 2);  // [4096][6144]
  short* vT    = (short*)take((size_t)BATCH_ * DIM_ * SEQ_ * 2);
  short* attno = (short*)take((size_t)TOK_ * DIM_ * 2);      // bf16
  short* attn  = (short*)take((size_t)BATCH_ * SEQ_ * SEQ_ * 2);
  float* cbias = (float*)take((size_t)3 * DIM_ * 4);
  short* ffn1  = qkv;          // alias over qkv+vT (dead after PV)
  short* h2    = h_bf;         // alias (h dead after QKV)

  const dim3 blk(256), gblk(512);
  // weight convert+transpose (batched QKV + w1 + w2)
  cvt3_transpose64<<<dim3(DIM_/64, DIM_/64, 3), blk, 0, stream>>>(wq, wk, wv, wqkvT);
  cvt_transpose64<<<dim3(HID_/64, DIM_/64), blk, 0, stream>>>(w1, w1T, DIM_, HID_);
  cvt_transpose64<<<dim3(DIM_/64, HID_/64), blk, 0, stream>>>(w2, w2T, HID_, DIM_);
  concat_bias_kernel<<<24, blk, 0, stream>>>(bq, bk, bv, cbias);
  // LN1
  ln_kernel<<<TOK_, blk, 0, stream>>>(x, nullptr, g1, b1, h_bf, 0);
  // fused QKV (gemm_bn128 3-slot, 768 wg = 3 full rounds)
  gemm_bn128<0><<<dim3(6144/128, TOK_/256, 1), gblk, 0, stream>>>(
      h_bf, wqkvT, qkv, cbias, nullptr, TOK_, 6144, DIM_, DIM_, DIM_, 6144, 0, 0, 0);
  // scores (scale+mask fused, causal skip) -> bf16 attn
  gemm_hi<4,1><<<dim3(SEQ_/256, SEQ_/128, BATCH_), gblk, 0, stream>>>(
      qkv, qkv + DIM_, attn, nullptr, mask, SEQ_, SEQ_, DIM_, 6144, 6144, SEQ_,
      (long long)SEQ_ * 6144, (long long)SEQ_ * 6144, (long long)SEQ_ * SEQ_);
  // causal in-place softmax
  softmax_causal_kernel<<<BATCH_ * SEQ_, blk, 0, stream>>>(attn);
  // V transpose: (B,S,D) strided in qkv -> vT (B,D,S)
  transpose_bf16_kernel<<<dim3(DIM_/32, SEQ_/32, BATCH_), blk, 0, stream>>>(
      qkv + 2*DIM_, vT, 6144, SEQ_, (long long)SEQ_ * 6144, (long long)DIM_ * SEQ_);
  // attn_out = probs @ V (causal K-cap) -> bf16
  gemm_hi<5,2><<<dim3(DIM_/256, SEQ_/128, BATCH_), gblk, 0, stream>>>(
      attn, vT, attno, nullptr, nullptr, SEQ_, DIM_, SEQ_, SEQ_, SEQ_, DIM_,
      (long long)SEQ_ * SEQ_, (long long)DIM_ * SEQ_, (long long)SEQ_ * DIM_);
  // LN2 over x + attn_out(bf16)
  ln_kernel<<<TOK_, blk, 0, stream>>>(x, attno, g2, b2, h2, 2);
  // FFN1 (gemm_hi, 1024 wg = 2 full rounds @ 2 wg/CU): gelu(h2@w1+b1) -> bf16
  gemm_hi<2,0><<<dim3(HID_/256, TOK_/128, 1), gblk, 0, stream>>>(
      h2, w1T, ffn1, bw1, nullptr, TOK_, HID_, DIM_, DIM_, DIM_, HID_, 0, 0, 0);
  // FFN2 (gemm_hi 3-slot, 2 wg/CU): x + (ffn1 @ w2 + b2) -> fp32 d_out
  gemm_hi<3,0><<<dim3(DIM_/256, TOK_/128, 1), gblk, 0, stream>>>(
      ffn1, w2T, out, bw2, x, TOK_, DIM_, HID_, HID_, HID_, DIM_, 0, 0, 0);
}